// Round 13
// baseline (208.023 us; speedup 1.0000x reference)
//
#include <hip/hip_runtime.h>
#include <hip/hip_bf16.h>
#include <stdint.h>

// B=1024, N=16, D=64, H=64, A=64 -> 16384 nodes. All tensors fp32.
#define NNODE 16384
#define TAU_ 0.01f
#define EPSG 1e-10f

// ---- workspace layout (float offsets) ----
#define OFF_WENC 0
#define OFF_BENC 4096
#define OFF_WIHF_H 4160      // 192x128 bf16 = 24576 ushort = 12288 fl
#define OFF_WIHF_L 16448
#define OFF_WHHF_H 28736     // 192x64 bf16 hi
#define OFF_BIHF 41024
#define OFF_BHHF 41216
#define OFF_WIHB_H 41408
#define OFF_WIHB_L 53696
#define OFF_WHHB_H 65984
#define OFF_BIHB 78272
#define OFF_BHHB 78464
#define OFF_WHARD 78656
#define OFF_BHARD 78912
#define OFF_WQT_H 78914      // Wq^T 64x64: 4096 ushort = 2048 fl
#define OFF_WQT_L 80962
#define OFF_WKT_H 83010
#define OFF_WKT_L 85058
#define OFF_WVT_H 87106
#define OFF_WVT_L 89154
#define OFF_BV 91202
#define OFF_WIHC_H 91266     // 192x64: 12288 ushort = 6144 fl
#define OFF_WIHC_L 97410
#define OFF_WHHC_H 103554
#define OFF_WHHC_L 109698
#define OFF_BIHC 115842
#define OFF_BHHC 116034
#define OFF_WENCT_H 118784   // Wenc^T bf16 hi: 64x64
#define OFF_WENCT_L 120832
#define OFF_YF 131072        // (unused since fusion; kept for layout stability)
#define OFF_YB (OFF_YF + 491520)
#define WS_FLOATS (OFF_YB + 491520)

typedef float  v4f __attribute__((ext_vector_type(4)));
typedef short  v8s __attribute__((ext_vector_type(8)));

// v_rcp_f32 (1-ulp approx) instead of precise fp32 division (R6: -31 us).
__device__ __forceinline__ float rcpf(float x){ return __builtin_amdgcn_rcpf(x); }
__device__ __forceinline__ float sigf(float x){ return rcpf(1.0f + __expf(-x)); }
__device__ __forceinline__ float tanhfast(float x){ return 1.0f - 2.0f*rcpf(__expf(2.0f*x)+1.0f); }
__device__ __forceinline__ unsigned short f2bf(float f){
  __hip_bfloat16 h = __float2bfloat16(f);
  return *reinterpret_cast<unsigned short*>(&h);
}
__device__ __forceinline__ float bf2f(unsigned short u){
  union { unsigned int i; float f; } v; v.i = ((unsigned int)u) << 16; return v.f;
}

// ---------------- K0: merged prep (copies + bf16 hi/lo splits) -------------
struct Prep {
  const float* s[20];
  int n[20];
  int o[20];
};
__global__ void k_prep(Prep p,
                       const float* __restrict__ wenc,
                       const float* __restrict__ wihf, const float* __restrict__ wihb,
                       const float* __restrict__ whhf, const float* __restrict__ whhb,
                       const float* __restrict__ wq,   const float* __restrict__ wk,
                       const float* __restrict__ wv,   const float* __restrict__ wihc,
                       const float* __restrict__ whhc,
                       float* __restrict__ ws){
  int a = blockIdx.y;
  int i = blockIdx.x * blockDim.x + threadIdx.x;
  if (a < 20){
    if (i < p.n[a]) ws[p.o[a] + i] = p.s[a][i];
    return;
  }
  a -= 20;
  if (a == 0 || (a >= 5 && a <= 7)){
    if (i < 4096){
      const float* src = (a==0) ? wenc : (a==5) ? wq : (a==6) ? wk : wv;
      int oh = (a==0) ? OFF_WENCT_H : (a==5) ? OFF_WQT_H : (a==6) ? OFF_WKT_H : OFF_WVT_H;
      int ol = (a==0) ? OFF_WENCT_L : oh + 2048;
      float x = src[((i & 63) << 6) | (i >> 6)];   // T[r][c] = src[c][r]
      unsigned short h = f2bf(x);
      unsigned short l = f2bf(x - bf2f(h));
      ((unsigned short*)(ws + oh))[i] = h;
      ((unsigned short*)(ws + ol))[i] = l;
    }
  } else if (a == 1 || a == 2){
    if (i < 24576){
      float x = (a == 1 ? wihf : wihb)[i];
      unsigned short h = f2bf(x);
      unsigned short l = f2bf(x - bf2f(h));
      ((unsigned short*)(ws + (a == 1 ? OFF_WIHF_H : OFF_WIHB_H)))[i] = h;
      ((unsigned short*)(ws + (a == 1 ? OFF_WIHF_L : OFF_WIHB_L)))[i] = l;
    }
  } else if (a == 3 || a == 4){
    if (i < 12288){
      float x = (a == 3 ? whhf : whhb)[i];
      ((unsigned short*)(ws + (a == 3 ? OFF_WHHF_H : OFF_WHHB_H)))[i] = f2bf(x);
    }
  } else {
    if (i < 12288){
      float x = (a == 8 ? wihc : whhc)[i];
      unsigned short h = f2bf(x);
      unsigned short l = f2bf(x - bf2f(h));
      int oh = (a == 8 ? OFF_WIHC_H : OFF_WHHC_H);
      ((unsigned short*)(ws + oh))[i] = h;
      ((unsigned short*)(ws + oh + 6144))[i] = l;
    }
  }
}

// ---------------- K1: FUSED kernel, 16 nodes/block, 2 waves, dual-dir ------
// R13: 1024 blocks x 128 thr (2 waves).  Each wave handles its l-half for
// BOTH directions: the fwd and bwd recurrences are independent chains ->
// doubled per-wave ILP, and the per-step barrier spans only 2 waves
// (R9->R10 measured 8->4 waves worth 14 us; this is the next halving).
// LDS 39.75 KB -> 4 blocks/CU (grid-limited 1024/256 anyway).
// launch_bounds(128,1): VGPR cap 256 (empirical cap=256/arg2) -- dual-dir
// state ~200 regs worst case; compiler rematerializes A-frag loads from L2.
__global__ __launch_bounds__(128, 1) void k_main(const float* __restrict__ obs,
                                                 const float* __restrict__ hid,
                                                 const float* __restrict__ gum,
                                                 float* __restrict__ ws,
                                                 float* __restrict__ out){
  __shared__ float smem[10176];                       // 39.75 KB
  float* s_u2 = smem;                                 // 2 x [16][196] (dir*3136)
  unsigned short* s_B = (unsigned short*)(smem + 6272); // region B: 5632 ush
  unsigned short* s_obs_h = s_B;                      // [16][72] obs/h_enc hi
  unsigned short* s_obs_l = s_B + 1152;               // lo
  // loop aliases region B: h dbuf = s_B + dd*2816 + rb*1408, [16][88] ush
  // post-loop aliases: s_xh=s_B, s_xl=+1152, s_h0h=+2304, s_h0l=+3456
  float* s_red = smem + 9088;                         // 2 dir x 2 par x [16][2]
  float* s_y   = smem + 9216;                         // 2 dir x [16][15][2]
  // post-loop q/k/v/co alias s_u2 (dead after loop):
  float* s_q  = smem;                                 // [16][68] = 1088
  float* s_k  = smem + 1088;                          // [64][17] = 1088
  float* s_v  = smem + 2176;                          // [64][17] = 1088
  float* s_co = smem + 3264;                          // [15][16] = 240

  const int tid = threadIdx.x;
  const int nl  = tid & 63;
  const int lw  = __builtin_amdgcn_readfirstlane(tid >> 6);  // 0,1: l-half
  const int q4  = nl >> 4;
  const int i_c = nl & 15;
  const int node = i_c;              // 0..15 (one graph per block)
  const int base = blockIdx.x * 16;

  // ---- P0: stage obs bf16 hi/lo [node][72] (128 thr x 8 fl) ----
  {
    float4 a = *(const float4*)&obs[base*64 + tid*8];
    float4 b = *(const float4*)&obs[base*64 + tid*8 + 4];
    int nn = tid >> 3, d0 = (tid & 7)*8;
    union { v8s v; unsigned short u[8]; } H, L;
    float xs[8] = {a.x,a.y,a.z,a.w,b.x,b.y,b.z,b.w};
    #pragma unroll
    for (int e = 0; e < 8; e++){
      H.u[e] = f2bf(xs[e]);
      L.u[e] = f2bf(xs[e] - bf2f(H.u[e]));
    }
    *(v8s*)&s_obs_h[nn*72 + d0] = H.v;
    *(v8s*)&s_obs_l[nn*72 + d0] = L.v;
  }
  __syncthreads();

  // ---- P1: h_enc via MFMA; 2 waves x 2 lT tiles ----
  const float* benc = ws + OFF_BENC;
  const unsigned short* wtH = (const unsigned short*)(ws + OFF_WENCT_H);
  const unsigned short* wtL = (const unsigned short*)(ws + OFF_WENCT_L);
  v4f dEnc[2];
  {
    v8s obH[2], obL[2];
    #pragma unroll
    for (int kc = 0; kc < 2; kc++){
      int ba = node*72 + kc*32 + q4*8;
      obH[kc] = *(const v8s*)&s_obs_h[ba];
      obL[kc] = *(const v8s*)&s_obs_l[ba];
    }
    #pragma unroll
    for (int tt = 0; tt < 2; tt++){
      int lT = 2*lw + tt;
      float4 bi = *(const float4*)&benc[16*lT + 4*q4];
      v4f d = (v4f){bi.x, bi.y, bi.z, bi.w};
      #pragma unroll
      for (int kc = 0; kc < 2; kc++){
        int aa = (16*lT + i_c)*64 + kc*32 + q4*8;
        v8s aH = *(const v8s*)&wtH[aa];
        v8s aL = *(const v8s*)&wtL[aa];
        d = __builtin_amdgcn_mfma_f32_16x16x32_bf16(aH, obH[kc], d, 0,0,0);
        d = __builtin_amdgcn_mfma_f32_16x16x32_bf16(aH, obL[kc], d, 0,0,0);
        d = __builtin_amdgcn_mfma_f32_16x16x32_bf16(aL, obH[kc], d, 0,0,0);
      }
      dEnc[tt] = d;
    }
  }
  __syncthreads();
  #pragma unroll
  for (int tt = 0; tt < 2; tt++){
    int lT = 2*lw + tt;
    unsigned short hh[4], ll[4];
    #pragma unroll
    for (int r = 0; r < 4; r++){
      float v = fmaxf(dEnc[tt][r], 0.0f);
      hh[r] = f2bf(v);
      ll[r] = f2bf(v - bf2f(hh[r]));
    }
    int wa = node*72 + 16*lT + 4*q4;
    *(uint2*)&s_obs_h[wa] = make_uint2((unsigned)hh[0] | ((unsigned)hh[1]<<16),
                                       (unsigned)hh[2] | ((unsigned)hh[3]<<16));
    *(uint2*)&s_obs_l[wa] = make_uint2((unsigned)ll[0] | ((unsigned)ll[1]<<16),
                                       (unsigned)ll[2] | ((unsigned)ll[3]<<16));
  }
  __syncthreads();

  // h_enc B-frags (used by C, P2a, P2b)
  v8s hbH[2], hbL[2];
  #pragma unroll
  for (int kc = 0; kc < 2; kc++){
    int ba = node*72 + kc*32 + q4*8;
    hbH[kc] = *(const v8s*)&s_obs_h[ba];
    hbL[kc] = *(const v8s*)&s_obs_l[ba];
  }

  // ---- C: q/k/v MFMA into regs; 2 waves x 2 aT tiles ----
  v4f dq[2], dk[2], dv[2];
  {
    const unsigned short* wqH = (const unsigned short*)(ws + OFF_WQT_H);
    const unsigned short* wqL = (const unsigned short*)(ws + OFF_WQT_L);
    const unsigned short* wkH = (const unsigned short*)(ws + OFF_WKT_H);
    const unsigned short* wkL = (const unsigned short*)(ws + OFF_WKT_L);
    const unsigned short* wvH = (const unsigned short*)(ws + OFF_WVT_H);
    const unsigned short* wvL = (const unsigned short*)(ws + OFF_WVT_L);
    const float* bv = ws + OFF_BV;
    #pragma unroll
    for (int a2 = 0; a2 < 2; a2++){
      int aT = 2*lw + a2;
      v4f q_ = (v4f){0.f,0.f,0.f,0.f};
      v4f k_ = (v4f){0.f,0.f,0.f,0.f};
      float4 b4 = *(const float4*)&bv[16*aT + 4*q4];
      v4f v_ = (v4f){b4.x, b4.y, b4.z, b4.w};
      #pragma unroll
      for (int kc = 0; kc < 2; kc++){
        int ai = (16*aT + i_c)*64 + kc*32 + q4*8;
        v8s aH = *(const v8s*)&wqH[ai]; v8s aL = *(const v8s*)&wqL[ai];
        q_ = __builtin_amdgcn_mfma_f32_16x16x32_bf16(aH, hbH[kc], q_, 0,0,0);
        q_ = __builtin_amdgcn_mfma_f32_16x16x32_bf16(aH, hbL[kc], q_, 0,0,0);
        q_ = __builtin_amdgcn_mfma_f32_16x16x32_bf16(aL, hbH[kc], q_, 0,0,0);
        aH = *(const v8s*)&wkH[ai]; aL = *(const v8s*)&wkL[ai];
        k_ = __builtin_amdgcn_mfma_f32_16x16x32_bf16(aH, hbH[kc], k_, 0,0,0);
        k_ = __builtin_amdgcn_mfma_f32_16x16x32_bf16(aH, hbL[kc], k_, 0,0,0);
        k_ = __builtin_amdgcn_mfma_f32_16x16x32_bf16(aL, hbH[kc], k_, 0,0,0);
        aH = *(const v8s*)&wvH[ai]; aL = *(const v8s*)&wvL[ai];
        v_ = __builtin_amdgcn_mfma_f32_16x16x32_bf16(aH, hbH[kc], v_, 0,0,0);
        v_ = __builtin_amdgcn_mfma_f32_16x16x32_bf16(aH, hbL[kc], v_, 0,0,0);
        v_ = __builtin_amdgcn_mfma_f32_16x16x32_bf16(aL, hbH[kc], v_, 0,0,0);
      }
      dq[a2] = q_; dk[a2] = k_; dv[a2] = v_;
    }
  }

  // ---- P2: recurrence setup, BOTH dirs per wave ----
  v4f cbr[2][2], cbz[2][2], cbn[2][2], bhn4[2][2];
  v8s afr[2][2][2], afz[2][2][2], afn[2][2][2];
  float wh0[2][8], wh1[2][8];
  #pragma unroll
  for (int dd = 0; dd < 2; dd++){
    const float* bih = ws + (dd ? OFF_BIHB : OFF_BIHF);
    const float* bhh = ws + (dd ? OFF_BHHB : OFF_BHHF);
    const unsigned short* wiH = (const unsigned short*)(ws + (dd ? OFF_WIHB_H : OFF_WIHF_H));
    const unsigned short* wiL = (const unsigned short*)(ws + (dd ? OFF_WIHB_L : OFF_WIHF_L));
    const unsigned short* whHd = (const unsigned short*)(ws + (dd ? OFF_WHHB_H : OFF_WHHF_H));
    float* u2d = s_u2 + dd*3136;

    // P2a: u2
    #pragma unroll
    for (int m = 0; m < 6; m++){
      int T = 6*lw + m;
      v4f d = (v4f){0.f,0.f,0.f,0.f};
      #pragma unroll
      for (int kc = 0; kc < 2; kc++){
        int aa = (16*T + i_c)*128 + 64 + kc*32 + q4*8;
        v8s aH = *(const v8s*)&wiH[aa];
        v8s aL = *(const v8s*)&wiL[aa];
        d = __builtin_amdgcn_mfma_f32_16x16x32_bf16(aH, hbH[kc], d, 0,0,0);
        d = __builtin_amdgcn_mfma_f32_16x16x32_bf16(aH, hbL[kc], d, 0,0,0);
        d = __builtin_amdgcn_mfma_f32_16x16x32_bf16(aL, hbH[kc], d, 0,0,0);
      }
      *(v4f*)&u2d[node*196 + 16*T + 4*q4] = d;
    }

    // P2b: cb
    #pragma unroll
    for (int g = 0; g < 3; g++){
      #pragma unroll
      for (int t2 = 0; t2 < 2; t2++){
        int row0 = 64*g + 32*lw + 16*t2 + 4*q4;
        float4 bi = *(const float4*)&bih[row0];
        v4f d;
        if (g < 2){
          float4 bh = *(const float4*)&bhh[row0];
          d = (v4f){bi.x+bh.x, bi.y+bh.y, bi.z+bh.z, bi.w+bh.w};
        } else {
          d = (v4f){bi.x, bi.y, bi.z, bi.w};
        }
        int T = (64*g + 32*lw + 16*t2) >> 4;
        #pragma unroll
        for (int kc = 0; kc < 2; kc++){
          int aa = (16*T + i_c)*128 + kc*32 + q4*8;
          v8s aH = *(const v8s*)&wiH[aa];
          v8s aL = *(const v8s*)&wiL[aa];
          d = __builtin_amdgcn_mfma_f32_16x16x32_bf16(aH, hbH[kc], d, 0,0,0);
          d = __builtin_amdgcn_mfma_f32_16x16x32_bf16(aH, hbL[kc], d, 0,0,0);
          d = __builtin_amdgcn_mfma_f32_16x16x32_bf16(aL, hbH[kc], d, 0,0,0);
        }
        if (g == 0) cbr[dd][t2] = d; else if (g == 1) cbz[dd][t2] = d; else cbn[dd][t2] = d;
      }
    }
    #pragma unroll
    for (int t2 = 0; t2 < 2; t2++){
      int row0 = 128 + 32*lw + 16*t2 + 4*q4;
      float4 nh = *(const float4*)&bhh[row0];
      bhn4[dd][t2] = (v4f){nh.x, nh.y, nh.z, nh.w};
    }

    // P2c: Whh A-frags
    #pragma unroll
    for (int t2 = 0; t2 < 2; t2++){
      #pragma unroll
      for (int kc = 0; kc < 2; kc++){
        #pragma unroll
        for (int g = 0; g < 3; g++){
          int row = g*64 + 32*lw + 16*t2 + i_c;
          v8s a = *(const v8s*)&whHd[row*64 + kc*32 + q4*8];
          if (g == 0) afr[dd][t2][kc] = a;
          else if (g == 1) afz[dd][t2][kc] = a;
          else afn[dd][t2][kc] = a;
        }
      }
    }

    const float* whard = ws + OFF_WHARD + dd*128;
    #pragma unroll
    for (int t2 = 0; t2 < 2; t2++){
      #pragma unroll
      for (int r = 0; r < 4; r++){
        int l = 32*lw + 16*t2 + 4*q4 + r;
        wh0[dd][t2*4+r] = whard[l*2];
        wh1[dd][t2*4+r] = whard[l*2+1];
      }
    }
  }
  __syncthreads();   // u2 visible; s_obs dead -> region B reusable as h dbuf

  // ---- P3: 15-step recurrence, both dirs IN THIS WAVE (dual chains) ------
  float hv[2][8];
  #pragma unroll
  for (int dd = 0; dd < 2; dd++)
    #pragma unroll
    for (int m = 0; m < 8; m++) hv[dd][m] = 0.0f;

  for (int kk = 0; kk < 15; kk++){
    const int rb = kk & 1;
    const int wb = (kk + 1) & 1;
    const int tt0 = kk;           // fwd t
    const int tt1 = 14 - kk;      // bwd t

    v8s b0[2], b1[2];
    if (kk > 0){
      #pragma unroll
      for (int dd = 0; dd < 2; dd++){
        const unsigned short* rp = s_B + dd*2816 + rb*1408 + node*88 + q4*8;
        b0[dd] = *(const v8s*)(rp);
        b1[dd] = *(const v8s*)(rp + 32);
      }
    }

    float a0p[2] = {0.f, 0.f}, a1p[2] = {0.f, 0.f};
    #pragma unroll
    for (int dd = 0; dd < 2; dd++){
      const int t  = dd ? tt1 : tt0;
      const int jl = t + (t >= i_c ? 1 : 0);
      const float* u2d = s_u2 + dd*3136;
      #pragma unroll
      for (int t2 = 0; t2 < 2; t2++){
        int l0 = 32*lw + 16*t2 + 4*q4;
        v4f dr = cbr[dd][t2], dz = cbz[dd][t2];
        v4f dn = (v4f){0.f,0.f,0.f,0.f};
        if (kk > 0){
          dr = __builtin_amdgcn_mfma_f32_16x16x32_bf16(afr[dd][t2][0], b0[dd], dr, 0,0,0);
          dr = __builtin_amdgcn_mfma_f32_16x16x32_bf16(afr[dd][t2][1], b1[dd], dr, 0,0,0);
          dz = __builtin_amdgcn_mfma_f32_16x16x32_bf16(afz[dd][t2][0], b0[dd], dz, 0,0,0);
          dz = __builtin_amdgcn_mfma_f32_16x16x32_bf16(afz[dd][t2][1], b1[dd], dz, 0,0,0);
          dn = __builtin_amdgcn_mfma_f32_16x16x32_bf16(afn[dd][t2][0], b0[dd], dn, 0,0,0);
          dn = __builtin_amdgcn_mfma_f32_16x16x32_bf16(afn[dd][t2][1], b1[dd], dn, 0,0,0);
        }
        v4f ur = *(const v4f*)&u2d[jl*196 +       l0];
        v4f uz = *(const v4f*)&u2d[jl*196 +  64 + l0];
        v4f un = *(const v4f*)&u2d[jl*196 + 128 + l0];
        float hn[4];
        #pragma unroll
        for (int r = 0; r < 4; r++){
          float rg = sigf(dr[r] + ur[r]);
          float zg = sigf(dz[r] + uz[r]);
          float ng = tanhfast(cbn[dd][t2][r] + un[r] + rg*(bhn4[dd][t2][r] + dn[r]));
          float hnew = (1.0f - zg)*ng + zg*hv[dd][t2*4+r];
          hv[dd][t2*4+r] = hnew;
          hn[r] = hnew;
          a0p[dd] += hnew*wh0[dd][t2*4+r];
          a1p[dd] += hnew*wh1[dd][t2*4+r];
        }
        unsigned int p0 = (unsigned int)f2bf(hn[0]) | ((unsigned int)f2bf(hn[1]) << 16);
        unsigned int p1 = (unsigned int)f2bf(hn[2]) | ((unsigned int)f2bf(hn[3]) << 16);
        *(uint2*)(s_B + dd*2816 + wb*1408 + node*88 + l0) = make_uint2(p0, p1);
      }
    }

    #pragma unroll
    for (int dd = 0; dd < 2; dd++){
      a0p[dd] += __shfl_xor(a0p[dd], 16); a0p[dd] += __shfl_xor(a0p[dd], 32);
      a1p[dd] += __shfl_xor(a1p[dd], 16); a1p[dd] += __shfl_xor(a1p[dd], 32);
    }
    if (lw == 0 && q4 == 0){
      *(float2*)&s_red[       rb*32 + node*2] = make_float2(a0p[0], a1p[0]);
      *(float2*)&s_red[64   + rb*32 + node*2] = make_float2(a0p[1], a1p[1]);
    }
    __syncthreads();
    if (lw == 1 && q4 == 0){
      float2 p0 = *(const float2*)&s_red[       rb*32 + node*2];
      float2 p1 = *(const float2*)&s_red[64   + rb*32 + node*2];
      *(float2*)&s_y[      (node*15 + tt0)*2] = make_float2(a0p[0] + p0.x, a1p[0] + p0.y);
      *(float2*)&s_y[480 + (node*15 + tt1)*2] = make_float2(a0p[1] + p1.x, a1p[1] + p1.y);
    }
  }
  __syncthreads();   // s_y complete; s_u2 dead -> q/k/v/co region writable

  // ---- D': q/k/v regs -> LDS ----
  #pragma unroll
  for (int a2 = 0; a2 < 2; a2++){
    int aT = 2*lw + a2;
    *(v4f*)&s_q[node*68 + 16*aT + 4*q4] = dq[a2];
    #pragma unroll
    for (int r = 0; r < 4; r++){
      s_k[(16*aT + 4*q4 + r)*17 + node] = dk[a2][r];
      s_v[(16*aT + 4*q4 + r)*17 + node] = fmaxf(dv[a2][r], 0.f);
    }
  }
  __syncthreads();

  // ---- E: scores + softmax + gumbel coeffs (128 thr: 16 nodes x 8 slices) -
  const int n2  = tid >> 3;            // 0..15
  const int asl = tid & 7;
  {
    float4 aq0 = *(const float4*)&s_q[n2*68 + asl*8];
    float4 aq1 = *(const float4*)&s_q[n2*68 + asl*8 + 4];
    float sc[15];
    #pragma unroll
    for (int t = 0; t < 15; t++){
      int jl = t + (t >= n2 ? 1 : 0);
      const float* kp = s_k + (asl*8)*17 + jl;
      float s = aq0.x*kp[0]  + aq0.y*kp[17]  + aq0.z*kp[34]  + aq0.w*kp[51]
              + aq1.x*kp[68] + aq1.y*kp[85]  + aq1.z*kp[102] + aq1.w*kp[119];
      s += __shfl_xor(s, 1); s += __shfl_xor(s, 2); s += __shfl_xor(s, 4);
      sc[t] = s * 0.125f;
    }
    float m = sc[0];
    #pragma unroll
    for (int t = 1; t < 15; t++) m = fmaxf(m, sc[t]);
    float den = 0.f;
    #pragma unroll
    for (int t = 0; t < 15; t++) den += __expf(sc[t]-m);
    float rden = rcpf(den);
    const float bh0 = ws[OFF_BHARD], bh1 = ws[OFF_BHARD+1];
    #pragma unroll
    for (int t = 0; t < 15; t++){
      if ((t & 7) == asl){
        int yi = (n2*15 + t)*2;
        float y0 = s_y[yi]     + s_y[480 + yi]     + bh0;
        float y1 = s_y[yi + 1] + s_y[480 + yi + 1] + bh1;
        float2 u2 = *(const float2*)&gum[((base + n2)*15 + t)*2];
        float g0 = -__logf(-__logf(u2.x + EPSG) + EPSG);
        float g1 = -__logf(-__logf(u2.y + EPSG) + EPSG);
        float w  = sigf(((y1+g1) - (y0+g0)) * (1.0f/TAU_));
        s_co[t*16 + n2] = __expf(sc[t]-m)*rden*w;
      }
    }
  }
  __syncthreads();

  // ---- F: x = sum_t coeff*v -> bf16 frags; h0 staging ----
  unsigned short* s_xh  = s_B;
  unsigned short* s_xl  = s_B + 1152;
  unsigned short* s_h0h = s_B + 2304;
  unsigned short* s_h0l = s_B + 3456;
  {
    float xa[8];
    #pragma unroll
    for (int il = 0; il < 8; il++) xa[il] = 0.f;
    #pragma unroll
    for (int t = 0; t < 15; t++){
      float c = s_co[t*16 + n2];
      int jl = t + (t >= n2 ? 1 : 0);
      const float* vp = s_v + (asl*8)*17 + jl;
      xa[0] += c*vp[0];   xa[1] += c*vp[17];  xa[2] += c*vp[34];  xa[3] += c*vp[51];
      xa[4] += c*vp[68];  xa[5] += c*vp[85];  xa[6] += c*vp[102]; xa[7] += c*vp[119];
    }
    union { v8s v; unsigned short u[8]; } XH, XL;
    #pragma unroll
    for (int e = 0; e < 8; e++){
      XH.u[e] = f2bf(xa[e]);
      XL.u[e] = f2bf(xa[e] - bf2f(XH.u[e]));
    }
    *(v8s*)&s_xh[n2*72 + asl*8] = XH.v;
    *(v8s*)&s_xl[n2*72 + asl*8] = XL.v;
  }
  {
    float4 a = *(const float4*)&hid[base*64 + tid*8];
    float4 b = *(const float4*)&hid[base*64 + tid*8 + 4];
    int nn = tid >> 3, d0 = (tid & 7)*8;
    union { v8s v; unsigned short u[8]; } H, L;
    float xs[8] = {a.x,a.y,a.z,a.w,b.x,b.y,b.z,b.w};
    #pragma unroll
    for (int e = 0; e < 8; e++){
      H.u[e] = f2bf(xs[e]);
      L.u[e] = f2bf(xs[e] - bf2f(H.u[e]));
    }
    *(v8s*)&s_h0h[nn*72 + d0] = H.v;
    *(v8s*)&s_h0l[nn*72 + d0] = L.v;
  }
  __syncthreads();

  // ---- G: final GRU cell via MFMA; 2 waves x (3g x 2u) tiles ----
  {
    v8s xbH[2], xbL[2], h0H[2], h0L[2];
    #pragma unroll
    for (int kc = 0; kc < 2; kc++){
      int ba = node*72 + kc*32 + q4*8;
      xbH[kc] = *(const v8s*)&s_xh[ba];  xbL[kc] = *(const v8s*)&s_xl[ba];
      h0H[kc] = *(const v8s*)&s_h0h[ba]; h0L[kc] = *(const v8s*)&s_h0l[ba];
    }
    const unsigned short* wiH2 = (const unsigned short*)(ws + OFF_WIHC_H);
    const unsigned short* wiL2 = (const unsigned short*)(ws + OFF_WIHC_L);
    const unsigned short* whH2 = (const unsigned short*)(ws + OFF_WHHC_H);
    const unsigned short* whL2 = (const unsigned short*)(ws + OFF_WHHC_L);
    const float* bihc = ws + OFF_BIHC; const float* bhhc = ws + OFF_BHHC;
    v4f gi[3][2], gh[3][2];
    #pragma unroll
    for (int g = 0; g < 3; g++){
      #pragma unroll
      for (int uu = 0; uu < 2; uu++){
        int u = 2*lw + uu;
        int row0 = g*64 + 16*u + 4*q4;
        float4 bi = *(const float4*)&bihc[row0];
        float4 bh = *(const float4*)&bhhc[row0];
        v4f di, dh;
        if (g < 2){
          di = (v4f){bi.x+bh.x, bi.y+bh.y, bi.z+bh.z, bi.w+bh.w};
          dh = (v4f){0.f,0.f,0.f,0.f};
        } else {
          di = (v4f){bi.x, bi.y, bi.z, bi.w};
          dh = (v4f){bh.x, bh.y, bh.z, bh.w};
        }
        #pragma unroll
        for (int kc = 0; kc < 2; kc++){
          int ai = (g*64 + 16*u + i_c)*64 + kc*32 + q4*8;
          v8s aH = *(const v8s*)&wiH2[ai]; v8s aL = *(const v8s*)&wiL2[ai];
          di = __builtin_amdgcn_mfma_f32_16x16x32_bf16(aH, xbH[kc], di, 0,0,0);
          di = __builtin_amdgcn_mfma_f32_16x16x32_bf16(aH, xbL[kc], di, 0,0,0);
          di = __builtin_amdgcn_mfma_f32_16x16x32_bf16(aL, xbH[kc], di, 0,0,0);
          aH = *(const v8s*)&whH2[ai]; aL = *(const v8s*)&whL2[ai];
          dh = __builtin_amdgcn_mfma_f32_16x16x32_bf16(aH, h0H[kc], dh, 0,0,0);
          dh = __builtin_amdgcn_mfma_f32_16x16x32_bf16(aH, h0L[kc], dh, 0,0,0);
          dh = __builtin_amdgcn_mfma_f32_16x16x32_bf16(aL, h0H[kc], dh, 0,0,0);
        }
        gi[g][uu] = di; gh[g][uu] = dh;
      }
    }
    #pragma unroll
    for (int uu = 0; uu < 2; uu++){
      int l0 = 16*(2*lw + uu) + 4*q4;
      float4 h04 = *(const float4*)&hid[(base+node)*64 + l0];
      float hh4[4] = {h04.x, h04.y, h04.z, h04.w};
      float ho[4];
      #pragma unroll
      for (int r = 0; r < 4; r++){
        float rg = sigf(gi[0][uu][r] + gh[0][uu][r]);
        float zg = sigf(gi[1][uu][r] + gh[1][uu][r]);
        float ng = tanhfast(gi[2][uu][r] + rg*gh[2][uu][r]);
        ho[r] = (1.0f - zg)*ng + zg*hh4[r];
      }
      *(float4*)&out[(base+node)*64 + l0] = make_float4(ho[0], ho[1], ho[2], ho[3]);
    }
  }
}

extern "C" void kernel_launch(void* const* d_in, const int* in_sizes, int n_in,
                              void* d_out, int out_size, void* d_ws, size_t ws_size,
                              hipStream_t stream){
  if (ws_size < (size_t)WS_FLOATS * sizeof(float)) return;
  float* ws = (float*)d_ws;
  // f32 copies still needed; MFMA weights go through the bf16-split branch
  static const int offs[20] = {OFF_WENC, OFF_BENC, 0, 0, OFF_BIHF, OFF_BHHF,
      0, 0, OFF_BIHB, OFF_BHHB, OFF_WHARD, OFF_BHARD, 0, 0, 0,
      OFF_BV, 0, 0, OFF_BIHC, OFF_BHHC};
  Prep p;
  for (int i = 0; i < 20; i++){
    p.s[i] = (const float*)d_in[3 + i];
    p.n[i] = in_sizes[3 + i];
    p.o[i] = offs[i];
  }
  // zero out f32 copies replaced by bf16 splits:
  p.n[2] = 0; p.n[3] = 0; p.n[6] = 0; p.n[7] = 0;      // Wih_f/Whh_f/Wih_b/Whh_b
  p.n[12] = 0; p.n[13] = 0; p.n[14] = 0;               // Wq/Wk/Wv
  p.n[16] = 0; p.n[17] = 0;                            // Wih_c/Whh_c
  hipLaunchKernelGGL(k_prep, dim3(96, 30), dim3(256), 0, stream, p,
                     (const float*)d_in[3], (const float*)d_in[5], (const float*)d_in[9],
                     (const float*)d_in[6], (const float*)d_in[10],
                     (const float*)d_in[15], (const float*)d_in[16], (const float*)d_in[17],
                     (const float*)d_in[19], (const float*)d_in[20], ws);
  hipLaunchKernelGGL(k_main, dim3(1024), dim3(128), 0, stream,
                     (const float*)d_in[0], (const float*)d_in[1],
                     (const float*)d_in[2], ws, (float*)d_out);
}

// Round 14
// 188.028 us; speedup vs baseline: 1.1063x; 1.1063x over previous
//
#include <hip/hip_runtime.h>
#include <hip/hip_bf16.h>
#include <stdint.h>

// B=1024, N=16, D=64, H=64, A=64 -> 16384 nodes. All tensors fp32.
#define NNODE 16384
#define TAU_ 0.01f
#define EPSG 1e-10f

// ---- workspace layout (float offsets) ----
#define OFF_WENC 0
#define OFF_BENC 4096
#define OFF_WIHF_H 4160      // 192x128 bf16 = 24576 ushort = 12288 fl
#define OFF_WIHF_L 16448
#define OFF_WHHF_H 28736     // 192x64 bf16 hi
#define OFF_BIHF 41024
#define OFF_BHHF 41216
#define OFF_WIHB_H 41408
#define OFF_WIHB_L 53696
#define OFF_WHHB_H 65984
#define OFF_BIHB 78272
#define OFF_BHHB 78464
#define OFF_WHARD 78656
#define OFF_BHARD 78912
#define OFF_WQT_H 78914      // Wq^T 64x64: 4096 ushort = 2048 fl
#define OFF_WQT_L 80962
#define OFF_WKT_H 83010
#define OFF_WKT_L 85058
#define OFF_WVT_H 87106
#define OFF_WVT_L 89154
#define OFF_BV 91202
#define OFF_WIHC_H 91266     // 192x64: 12288 ushort = 6144 fl
#define OFF_WIHC_L 97410
#define OFF_WHHC_H 103554
#define OFF_WHHC_L 109698
#define OFF_BIHC 115842
#define OFF_BHHC 116034
#define OFF_WENCT_H 118784   // Wenc^T bf16 hi: 64x64
#define OFF_WENCT_L 120832
#define OFF_YF 131072        // (unused since fusion; kept for layout stability)
#define OFF_YB (OFF_YF + 491520)
#define WS_FLOATS (OFF_YB + 491520)

typedef float  v4f __attribute__((ext_vector_type(4)));
typedef short  v8s __attribute__((ext_vector_type(8)));

// v_rcp_f32 (1-ulp approx) instead of precise fp32 division (R6: -31 us).
__device__ __forceinline__ float rcpf(float x){ return __builtin_amdgcn_rcpf(x); }
__device__ __forceinline__ float sigf(float x){ return rcpf(1.0f + __expf(-x)); }
__device__ __forceinline__ float tanhfast(float x){ return 1.0f - 2.0f*rcpf(__expf(2.0f*x)+1.0f); }
__device__ __forceinline__ unsigned short f2bf(float f){
  __hip_bfloat16 h = __float2bfloat16(f);
  return *reinterpret_cast<unsigned short*>(&h);
}
__device__ __forceinline__ float bf2f(unsigned short u){
  union { unsigned int i; float f; } v; v.i = ((unsigned int)u) << 16; return v.f;
}

// ---------------- K0: merged prep (copies + bf16 hi/lo splits) -------------
// blockIdx.y 0..19: f32 copies (Prep table).  20..29: bf16 splits
// (a=0 WencT, 1/2 Wih_f/b, 3/4 Whh_f/b hi, 5/6/7 WqT/WkT/WvT, 8/9 Wihc/Whhc).
struct Prep {
  const float* s[20];
  int n[20];
  int o[20];
};
__global__ void k_prep(Prep p,
                       const float* __restrict__ wenc,
                       const float* __restrict__ wihf, const float* __restrict__ wihb,
                       const float* __restrict__ whhf, const float* __restrict__ whhb,
                       const float* __restrict__ wq,   const float* __restrict__ wk,
                       const float* __restrict__ wv,   const float* __restrict__ wihc,
                       const float* __restrict__ whhc,
                       float* __restrict__ ws){
  int a = blockIdx.y;
  int i = blockIdx.x * blockDim.x + threadIdx.x;
  if (a < 20){
    if (i < p.n[a]) ws[p.o[a] + i] = p.s[a][i];
    return;
  }
  a -= 20;
  if (a == 0 || (a >= 5 && a <= 7)){
    if (i < 4096){
      const float* src = (a==0) ? wenc : (a==5) ? wq : (a==6) ? wk : wv;
      int oh = (a==0) ? OFF_WENCT_H : (a==5) ? OFF_WQT_H : (a==6) ? OFF_WKT_H : OFF_WVT_H;
      int ol = (a==0) ? OFF_WENCT_L : oh + 2048;
      float x = src[((i & 63) << 6) | (i >> 6)];   // T[r][c] = src[c][r]
      unsigned short h = f2bf(x);
      unsigned short l = f2bf(x - bf2f(h));
      ((unsigned short*)(ws + oh))[i] = h;
      ((unsigned short*)(ws + ol))[i] = l;
    }
  } else if (a == 1 || a == 2){
    if (i < 24576){
      float x = (a == 1 ? wihf : wihb)[i];
      unsigned short h = f2bf(x);
      unsigned short l = f2bf(x - bf2f(h));
      ((unsigned short*)(ws + (a == 1 ? OFF_WIHF_H : OFF_WIHB_H)))[i] = h;
      ((unsigned short*)(ws + (a == 1 ? OFF_WIHF_L : OFF_WIHB_L)))[i] = l;
    }
  } else if (a == 3 || a == 4){
    if (i < 12288){
      float x = (a == 3 ? whhf : whhb)[i];
      ((unsigned short*)(ws + (a == 3 ? OFF_WHHF_H : OFF_WHHB_H)))[i] = f2bf(x);
    }
  } else {
    if (i < 12288){
      float x = (a == 8 ? wihc : whhc)[i];
      unsigned short h = f2bf(x);
      unsigned short l = f2bf(x - bf2f(h));
      int oh = (a == 8 ? OFF_WIHC_H : OFF_WHHC_H);
      ((unsigned short*)(ws + oh))[i] = h;
      ((unsigned short*)(ws + oh + 6144))[i] = l;
    }
  }
}

// ---------------- K1: FUSED end-to-end kernel, 16 nodes (one graph)/block --
// 1024 blocks x 256 thr (4 waves).  Waves 0-1: forward GRU; waves 2-3:
// backward -- concurrent recurrences, 4-wave barriers, 4 blocks/CU.
// MEASURED OPTIMUM of the wave-width sweep: 8-wave=111us, 4-wave=97us,
// 2-wave-dual-dir=117us (R9/R10-R12/R13) -- TLP beats ILP on this
// barrier-bound loop; do not re-trade occupancy for chain ILP.
// launch_bounds(256,2): VGPR cap 128 (empirical cap=256/arg2, 4x verified).
__global__ __launch_bounds__(256, 2) void k_main(const float* __restrict__ obs,
                                                 const float* __restrict__ hid,
                                                 const float* __restrict__ gum,
                                                 float* __restrict__ ws,
                                                 float* __restrict__ out){
  __shared__ float smem[10176];                       // 39.75 KB
  float* s_u2 = smem;                                 // 2 x [16][196] (dir*3136)
  unsigned short* s_B = (unsigned short*)(smem + 6272); // region B: 5632 ush
  unsigned short* s_obs_h = s_B;                      // [16][72] obs/h_enc hi
  unsigned short* s_obs_l = s_B + 1152;               // lo
  // loop aliases region B: h dbuf = s_B + dir*2816 + rb*1408, [16][88] ush
  // post-loop aliases: s_xh=s_B, s_xl=+1152, s_h0h=+2304, s_h0l=+3456
  float* s_red = smem + 9088;                         // 2 dir x 2 par x [16][2]
  float* s_y   = smem + 9216;                         // 2 dir x [16][15][2]
  // post-loop q/k/v/co alias s_u2 (dead after loop):
  float* s_q  = smem;                                 // [16][68] = 1088
  float* s_k  = smem + 1088;                          // [64][17] = 1088
  float* s_v  = smem + 2176;                          // [64][17] = 1088
  float* s_co = smem + 3264;                          // [15][16] = 240

  const int tid = threadIdx.x;
  const int nl  = tid & 63;
  const int grp = __builtin_amdgcn_readfirstlane(tid >> 6);  // 0..3
  const int dir = grp >> 1;          // 0 fwd, 1 bwd
  const int lw  = grp & 1;           // recurrence l-half
  const int hi2 = grp;               // 0..3: lT (P1) / aT (C) / u (G)
  const int q4  = nl >> 4;
  const int i_c = nl & 15;
  const int node = i_c;              // 0..15 (one graph per block)
  const int base = blockIdx.x * 16;

  // ---- P0: stage obs bf16 hi/lo [node][72] (256 thr x 4 fl) ----
  {
    float4 a = *(const float4*)&obs[base*64 + tid*4];
    int nn = tid >> 4, d0 = (tid & 15)*4;
    unsigned short hh[4], ll[4];
    float xs[4] = {a.x,a.y,a.z,a.w};
    #pragma unroll
    for (int e = 0; e < 4; e++){
      hh[e] = f2bf(xs[e]);
      ll[e] = f2bf(xs[e] - bf2f(hh[e]));
    }
    *(uint2*)&s_obs_h[nn*72 + d0] = make_uint2((unsigned)hh[0] | ((unsigned)hh[1]<<16),
                                               (unsigned)hh[2] | ((unsigned)hh[3]<<16));
    *(uint2*)&s_obs_l[nn*72 + d0] = make_uint2((unsigned)ll[0] | ((unsigned)ll[1]<<16),
                                               (unsigned)ll[2] | ((unsigned)ll[3]<<16));
  }
  __syncthreads();

  // ---- P1: h_enc = relu(obs @ Wenc + b) via MFMA; 4 waves x 1 lT tile ----
  const float* benc = ws + OFF_BENC;
  const unsigned short* wtH = (const unsigned short*)(ws + OFF_WENCT_H);
  const unsigned short* wtL = (const unsigned short*)(ws + OFF_WENCT_L);
  v4f dEnc;
  {
    v8s obH[2], obL[2];
    #pragma unroll
    for (int kc = 0; kc < 2; kc++){
      int ba = node*72 + kc*32 + q4*8;
      obH[kc] = *(const v8s*)&s_obs_h[ba];
      obL[kc] = *(const v8s*)&s_obs_l[ba];
    }
    float4 bi = *(const float4*)&benc[16*hi2 + 4*q4];
    v4f d = (v4f){bi.x, bi.y, bi.z, bi.w};
    #pragma unroll
    for (int kc = 0; kc < 2; kc++){
      int aa = (16*hi2 + i_c)*64 + kc*32 + q4*8;
      v8s aH = *(const v8s*)&wtH[aa];
      v8s aL = *(const v8s*)&wtL[aa];
      d = __builtin_amdgcn_mfma_f32_16x16x32_bf16(aH, obH[kc], d, 0,0,0);
      d = __builtin_amdgcn_mfma_f32_16x16x32_bf16(aH, obL[kc], d, 0,0,0);
      d = __builtin_amdgcn_mfma_f32_16x16x32_bf16(aL, obH[kc], d, 0,0,0);
    }
    dEnc = d;
  }
  __syncthreads();   // all obs frag reads done -> in-place write-back
  {
    unsigned short hh[4], ll[4];
    #pragma unroll
    for (int r = 0; r < 4; r++){
      float v = fmaxf(dEnc[r], 0.0f);
      hh[r] = f2bf(v);
      ll[r] = f2bf(v - bf2f(hh[r]));
    }
    int wa = node*72 + 16*hi2 + 4*q4;
    *(uint2*)&s_obs_h[wa] = make_uint2((unsigned)hh[0] | ((unsigned)hh[1]<<16),
                                       (unsigned)hh[2] | ((unsigned)hh[3]<<16));
    *(uint2*)&s_obs_l[wa] = make_uint2((unsigned)ll[0] | ((unsigned)ll[1]<<16),
                                       (unsigned)ll[2] | ((unsigned)ll[3]<<16));
  }
  __syncthreads();

  // h_enc B-frags for this wave's node (used by C, P2a, P2b)
  v8s hbH[2], hbL[2];
  #pragma unroll
  for (int kc = 0; kc < 2; kc++){
    int ba = node*72 + kc*32 + q4*8;
    hbH[kc] = *(const v8s*)&s_obs_h[ba];
    hbL[kc] = *(const v8s*)&s_obs_l[ba];
  }

  // ---- C: q/k/v MFMA into regs; 4 waves x 1 aT tile ----
  v4f dq, dk, dv;
  {
    const unsigned short* wqH = (const unsigned short*)(ws + OFF_WQT_H);
    const unsigned short* wqL = (const unsigned short*)(ws + OFF_WQT_L);
    const unsigned short* wkH = (const unsigned short*)(ws + OFF_WKT_H);
    const unsigned short* wkL = (const unsigned short*)(ws + OFF_WKT_L);
    const unsigned short* wvH = (const unsigned short*)(ws + OFF_WVT_H);
    const unsigned short* wvL = (const unsigned short*)(ws + OFF_WVT_L);
    const float* bv = ws + OFF_BV;
    v4f q_ = (v4f){0.f,0.f,0.f,0.f};
    v4f k_ = (v4f){0.f,0.f,0.f,0.f};
    float4 b4 = *(const float4*)&bv[16*hi2 + 4*q4];
    v4f v_ = (v4f){b4.x, b4.y, b4.z, b4.w};
    #pragma unroll
    for (int kc = 0; kc < 2; kc++){
      int ai = (16*hi2 + i_c)*64 + kc*32 + q4*8;
      v8s aH = *(const v8s*)&wqH[ai]; v8s aL = *(const v8s*)&wqL[ai];
      q_ = __builtin_amdgcn_mfma_f32_16x16x32_bf16(aH, hbH[kc], q_, 0,0,0);
      q_ = __builtin_amdgcn_mfma_f32_16x16x32_bf16(aH, hbL[kc], q_, 0,0,0);
      q_ = __builtin_amdgcn_mfma_f32_16x16x32_bf16(aL, hbH[kc], q_, 0,0,0);
      aH = *(const v8s*)&wkH[ai]; aL = *(const v8s*)&wkL[ai];
      k_ = __builtin_amdgcn_mfma_f32_16x16x32_bf16(aH, hbH[kc], k_, 0,0,0);
      k_ = __builtin_amdgcn_mfma_f32_16x16x32_bf16(aH, hbL[kc], k_, 0,0,0);
      k_ = __builtin_amdgcn_mfma_f32_16x16x32_bf16(aL, hbH[kc], k_, 0,0,0);
      aH = *(const v8s*)&wvH[ai]; aL = *(const v8s*)&wvL[ai];
      v_ = __builtin_amdgcn_mfma_f32_16x16x32_bf16(aH, hbH[kc], v_, 0,0,0);
      v_ = __builtin_amdgcn_mfma_f32_16x16x32_bf16(aH, hbL[kc], v_, 0,0,0);
      v_ = __builtin_amdgcn_mfma_f32_16x16x32_bf16(aL, hbH[kc], v_, 0,0,0);
    }
    dq = q_; dk = k_; dv = v_;
  }

  // ---- P2: recurrence setup, per-dir weights ----
  const float* bih = ws + (dir ? OFF_BIHB : OFF_BIHF);
  const float* bhh = ws + (dir ? OFF_BHHB : OFF_BHHF);
  const unsigned short* wiH = (const unsigned short*)(ws + (dir ? OFF_WIHB_H : OFF_WIHF_H));
  const unsigned short* wiL = (const unsigned short*)(ws + (dir ? OFF_WIHB_L : OFF_WIHF_L));
  const unsigned short* whH = (const unsigned short*)(ws + (dir ? OFF_WHHB_H : OFF_WHHF_H));
  float* myu2 = s_u2 + dir*3136;

  // P2a: u2[j][row] = WihR . h_enc[j]; 2 waves/dir x 6 M-tiles
  #pragma unroll
  for (int m = 0; m < 6; m++){
    int T = 6*lw + m;
    v4f d = (v4f){0.f,0.f,0.f,0.f};
    #pragma unroll
    for (int kc = 0; kc < 2; kc++){
      int aa = (16*T + i_c)*128 + 64 + kc*32 + q4*8;
      v8s aH = *(const v8s*)&wiH[aa];
      v8s aL = *(const v8s*)&wiL[aa];
      d = __builtin_amdgcn_mfma_f32_16x16x32_bf16(aH, hbH[kc], d, 0,0,0);
      d = __builtin_amdgcn_mfma_f32_16x16x32_bf16(aH, hbL[kc], d, 0,0,0);
      d = __builtin_amdgcn_mfma_f32_16x16x32_bf16(aL, hbH[kc], d, 0,0,0);
    }
    *(v4f*)&myu2[node*196 + 16*T + 4*q4] = d;
  }

  // P2b: cb (C-layout biased gate pre-activations)
  v4f cbr[2], cbz[2], cbn[2], bhn4[2];
  #pragma unroll
  for (int g = 0; g < 3; g++){
    #pragma unroll
    for (int t2 = 0; t2 < 2; t2++){
      int row0 = 64*g + 32*lw + 16*t2 + 4*q4;
      float4 bi = *(const float4*)&bih[row0];
      v4f d;
      if (g < 2){
        float4 bh = *(const float4*)&bhh[row0];
        d = (v4f){bi.x+bh.x, bi.y+bh.y, bi.z+bh.z, bi.w+bh.w};
      } else {
        d = (v4f){bi.x, bi.y, bi.z, bi.w};
      }
      int T = (64*g + 32*lw + 16*t2) >> 4;
      #pragma unroll
      for (int kc = 0; kc < 2; kc++){
        int aa = (16*T + i_c)*128 + kc*32 + q4*8;
        v8s aH = *(const v8s*)&wiH[aa];
        v8s aL = *(const v8s*)&wiL[aa];
        d = __builtin_amdgcn_mfma_f32_16x16x32_bf16(aH, hbH[kc], d, 0,0,0);
        d = __builtin_amdgcn_mfma_f32_16x16x32_bf16(aH, hbL[kc], d, 0,0,0);
        d = __builtin_amdgcn_mfma_f32_16x16x32_bf16(aL, hbH[kc], d, 0,0,0);
      }
      if (g == 0) cbr[t2] = d; else if (g == 1) cbz[t2] = d; else cbn[t2] = d;
    }
  }
  #pragma unroll
  for (int t2 = 0; t2 < 2; t2++){
    int row0 = 128 + 32*lw + 16*t2 + 4*q4;
    float4 nh = *(const float4*)&bhh[row0];
    bhn4[t2] = (v4f){nh.x, nh.y, nh.z, nh.w};
  }

  // P2c: Whh A-frags
  v8s afr[2][2], afz[2][2], afn[2][2];
  #pragma unroll
  for (int t2 = 0; t2 < 2; t2++){
    #pragma unroll
    for (int kc = 0; kc < 2; kc++){
      #pragma unroll
      for (int g = 0; g < 3; g++){
        int row = g*64 + 32*lw + 16*t2 + i_c;
        v8s a = *(const v8s*)&whH[row*64 + kc*32 + q4*8];
        if (g == 0) afr[t2][kc] = a; else if (g == 1) afz[t2][kc] = a; else afn[t2][kc] = a;
      }
    }
  }

  const float* whard = ws + OFF_WHARD + dir*128;
  float wh0[8], wh1[8];
  #pragma unroll
  for (int t2 = 0; t2 < 2; t2++){
    #pragma unroll
    for (int r = 0; r < 4; r++){
      int l = 32*lw + 16*t2 + 4*q4 + r;
      wh0[t2*4+r] = whard[l*2];
      wh1[t2*4+r] = whard[l*2+1];
    }
  }
  __syncthreads();   // u2 visible; s_obs dead -> region B reusable as h dbuf

  // ---- P3: 15-step recurrence, both dirs concurrent, u2 prefetched -------
  unsigned short* myh = s_B + dir*2816;   // 2 x [16][88] ush
  float hv[8];
  #pragma unroll
  for (int m = 0; m < 8; m++) hv[m] = 0.0f;

  // clamped j for step kk (clamp only matters for the dead kk=15 prefetch)
  #define JL_OF(kk2) ({ int t_ = dir ? (14 - (kk2)) : (kk2);                  \
                        int j_ = t_ + (t_ >= i_c ? 1 : 0);                     \
                        j_ < 0 ? 0 : (j_ > 15 ? 15 : j_); })

  v4f uP[2][3];
  {
    int jl0 = JL_OF(0);
    #pragma unroll
    for (int t2 = 0; t2 < 2; t2++){
      int l0 = 32*lw + 16*t2 + 4*q4;
      uP[t2][0] = *(const v4f*)&myu2[jl0*196 +       l0];
      uP[t2][1] = *(const v4f*)&myu2[jl0*196 +  64 + l0];
      uP[t2][2] = *(const v4f*)&myu2[jl0*196 + 128 + l0];
    }
  }

  for (int kk = 0; kk < 15; kk++){
    const int t  = dir ? (14 - kk) : kk;
    const int rb = kk & 1;
    const int wb = (kk + 1) & 1;

    v8s b0, b1;
    if (kk > 0){
      const unsigned short* rp = myh + rb*1408 + node*88 + q4*8;
      b0 = *(const v8s*)(rp);
      b1 = *(const v8s*)(rp + 32);
    }

    float a0p = 0.f, a1p = 0.f;
    #pragma unroll
    for (int t2 = 0; t2 < 2; t2++){
      int l0 = 32*lw + 16*t2 + 4*q4;
      v4f dr = cbr[t2], dz = cbz[t2];
      v4f dn = (v4f){0.f,0.f,0.f,0.f};
      if (kk > 0){
        dr = __builtin_amdgcn_mfma_f32_16x16x32_bf16(afr[t2][0], b0, dr, 0,0,0);
        dr = __builtin_amdgcn_mfma_f32_16x16x32_bf16(afr[t2][1], b1, dr, 0,0,0);
        dz = __builtin_amdgcn_mfma_f32_16x16x32_bf16(afz[t2][0], b0, dz, 0,0,0);
        dz = __builtin_amdgcn_mfma_f32_16x16x32_bf16(afz[t2][1], b1, dz, 0,0,0);
        dn = __builtin_amdgcn_mfma_f32_16x16x32_bf16(afn[t2][0], b0, dn, 0,0,0);
        dn = __builtin_amdgcn_mfma_f32_16x16x32_bf16(afn[t2][1], b1, dn, 0,0,0);
      }
      float hn[4];
      #pragma unroll
      for (int r = 0; r < 4; r++){
        float rg = sigf(dr[r] + uP[t2][0][r]);
        float zg = sigf(dz[r] + uP[t2][1][r]);
        float ng = tanhfast(cbn[t2][r] + uP[t2][2][r] + rg*(bhn4[t2][r] + dn[r]));
        float hnew = (1.0f - zg)*ng + zg*hv[t2*4+r];
        hv[t2*4+r] = hnew;
        hn[r] = hnew;
        a0p += hnew*wh0[t2*4+r];
        a1p += hnew*wh1[t2*4+r];
      }
      unsigned int p0 = (unsigned int)f2bf(hn[0]) | ((unsigned int)f2bf(hn[1]) << 16);
      unsigned int p1 = (unsigned int)f2bf(hn[2]) | ((unsigned int)f2bf(hn[3]) << 16);
      *(uint2*)(myh + wb*1408 + node*88 + l0) = make_uint2(p0, p1);
    }

    a0p += __shfl_xor(a0p, 16); a0p += __shfl_xor(a0p, 32);
    a1p += __shfl_xor(a1p, 16); a1p += __shfl_xor(a1p, 32);
    float* sr = s_red + dir*64 + rb*32;
    if (lw == 0 && q4 == 0)
      *(float2*)&sr[node*2] = make_float2(a0p, a1p);

    // prefetch u2 for step kk+1 (read-only data; latency hides under barrier)
    {
      int jlN = JL_OF(kk + 1);
      #pragma unroll
      for (int t2 = 0; t2 < 2; t2++){
        int l0 = 32*lw + 16*t2 + 4*q4;
        uP[t2][0] = *(const v4f*)&myu2[jlN*196 +       l0];
        uP[t2][1] = *(const v4f*)&myu2[jlN*196 +  64 + l0];
        uP[t2][2] = *(const v4f*)&myu2[jlN*196 + 128 + l0];
      }
    }
    __syncthreads();
    if (lw == 1 && q4 == 0){
      float2 pp = *(const float2*)&sr[node*2];
      *(float2*)&s_y[dir*480 + (node*15 + t)*2] = make_float2(a0p + pp.x, a1p + pp.y);
    }
  }
  #undef JL_OF
  __syncthreads();   // s_y complete; s_u2 dead -> q/k/v/co region writable

  // ---- D': q/k/v regs -> LDS ----
  {
    *(v4f*)&s_q[node*68 + 16*hi2 + 4*q4] = dq;
    #pragma unroll
    for (int r = 0; r < 4; r++){
      s_k[(16*hi2 + 4*q4 + r)*17 + node] = dk[r];
      s_v[(16*hi2 + 4*q4 + r)*17 + node] = fmaxf(dv[r], 0.f);
    }
  }
  __syncthreads();

  // ---- E: scores + softmax + gumbel coeffs (ALL 256 thr: 16 slices x 4a) --
  const int n2  = tid >> 4;            // 0..15
  const int asl = tid & 15;            // a-slice of 4
  {
    float4 aq0 = *(const float4*)&s_q[n2*68 + asl*4];
    float sc[15];
    #pragma unroll
    for (int t = 0; t < 15; t++){
      int jl = t + (t >= n2 ? 1 : 0);
      const float* kp = s_k + (asl*4)*17 + jl;
      float s = aq0.x*kp[0] + aq0.y*kp[17] + aq0.z*kp[34] + aq0.w*kp[51];
      s += __shfl_xor(s, 1); s += __shfl_xor(s, 2);
      s += __shfl_xor(s, 4); s += __shfl_xor(s, 8);
      sc[t] = s * 0.125f;
    }
    float m = sc[0];
    #pragma unroll
    for (int t = 1; t < 15; t++) m = fmaxf(m, sc[t]);
    float den = 0.f;
    #pragma unroll
    for (int t = 0; t < 15; t++) den += __expf(sc[t]-m);
    float rden = rcpf(den);
    const float bh0 = ws[OFF_BHARD], bh1 = ws[OFF_BHARD+1];
    #pragma unroll
    for (int t = 0; t < 15; t++){
      if ((t & 15) == asl){
        int yi = (n2*15 + t)*2;
        float y0 = s_y[yi]     + s_y[480 + yi]     + bh0;
        float y1 = s_y[yi + 1] + s_y[480 + yi + 1] + bh1;
        float2 u2 = *(const float2*)&gum[((base + n2)*15 + t)*2];
        float g0 = -__logf(-__logf(u2.x + EPSG) + EPSG);
        float g1 = -__logf(-__logf(u2.y + EPSG) + EPSG);
        float w  = sigf(((y1+g1) - (y0+g0)) * (1.0f/TAU_));
        s_co[t*16 + n2] = __expf(sc[t]-m)*rden*w;
      }
    }
  }
  __syncthreads();

  // ---- F: x = sum_t coeff*v -> bf16 frags (ALL 256 thr); h0 staging ------
  unsigned short* s_xh  = s_B;
  unsigned short* s_xl  = s_B + 1152;
  unsigned short* s_h0h = s_B + 2304;
  unsigned short* s_h0l = s_B + 3456;
  {
    float xa[4];
    #pragma unroll
    for (int il = 0; il < 4; il++) xa[il] = 0.f;
    #pragma unroll
    for (int t = 0; t < 15; t++){
      float c = s_co[t*16 + n2];
      int jl = t + (t >= n2 ? 1 : 0);
      const float* vp = s_v + (asl*4)*17 + jl;
      xa[0] += c*vp[0]; xa[1] += c*vp[17]; xa[2] += c*vp[34]; xa[3] += c*vp[51];
    }
    unsigned short xh[4], xl[4];
    #pragma unroll
    for (int e = 0; e < 4; e++){
      xh[e] = f2bf(xa[e]);
      xl[e] = f2bf(xa[e] - bf2f(xh[e]));
    }
    *(uint2*)&s_xh[n2*72 + asl*4] = make_uint2((unsigned)xh[0] | ((unsigned)xh[1]<<16),
                                               (unsigned)xh[2] | ((unsigned)xh[3]<<16));
    *(uint2*)&s_xl[n2*72 + asl*4] = make_uint2((unsigned)xl[0] | ((unsigned)xl[1]<<16),
                                               (unsigned)xl[2] | ((unsigned)xl[3]<<16));
  }
  {
    float4 a = *(const float4*)&hid[base*64 + tid*4];
    int nn = tid >> 4, d0 = (tid & 15)*4;
    unsigned short hh[4], ll[4];
    float xs[4] = {a.x,a.y,a.z,a.w};
    #pragma unroll
    for (int e = 0; e < 4; e++){
      hh[e] = f2bf(xs[e]);
      ll[e] = f2bf(xs[e] - bf2f(hh[e]));
    }
    *(uint2*)&s_h0h[nn*72 + d0] = make_uint2((unsigned)hh[0] | ((unsigned)hh[1]<<16),
                                             (unsigned)hh[2] | ((unsigned)hh[3]<<16));
    *(uint2*)&s_h0l[nn*72 + d0] = make_uint2((unsigned)ll[0] | ((unsigned)ll[1]<<16),
                                             (unsigned)ll[2] | ((unsigned)ll[3]<<16));
  }
  __syncthreads();

  // ---- G: final GRU cell via MFMA; 4 waves x 3 g-tiles ----
  {
    v8s xbH[2], xbL[2], h0H[2], h0L[2];
    #pragma unroll
    for (int kc = 0; kc < 2; kc++){
      int ba = node*72 + kc*32 + q4*8;
      xbH[kc] = *(const v8s*)&s_xh[ba];  xbL[kc] = *(const v8s*)&s_xl[ba];
      h0H[kc] = *(const v8s*)&s_h0h[ba]; h0L[kc] = *(const v8s*)&s_h0l[ba];
    }
    const unsigned short* wiH2 = (const unsigned short*)(ws + OFF_WIHC_H);
    const unsigned short* wiL2 = (const unsigned short*)(ws + OFF_WIHC_L);
    const unsigned short* whH2 = (const unsigned short*)(ws + OFF_WHHC_H);
    const unsigned short* whL2 = (const unsigned short*)(ws + OFF_WHHC_L);
    const float* bihc = ws + OFF_BIHC; const float* bhhc = ws + OFF_BHHC;
    v4f gi[3], gh[3];
    #pragma unroll
    for (int g = 0; g < 3; g++){
      int row0 = g*64 + 16*hi2 + 4*q4;
      float4 bi = *(const float4*)&bihc[row0];
      float4 bh = *(const float4*)&bhhc[row0];
      v4f di, dh;
      if (g < 2){
        di = (v4f){bi.x+bh.x, bi.y+bh.y, bi.z+bh.z, bi.w+bh.w};
        dh = (v4f){0.f,0.f,0.f,0.f};
      } else {
        di = (v4f){bi.x, bi.y, bi.z, bi.w};
        dh = (v4f){bh.x, bh.y, bh.z, bh.w};
      }
      #pragma unroll
      for (int kc = 0; kc < 2; kc++){
        int ai = (g*64 + 16*hi2 + i_c)*64 + kc*32 + q4*8;
        v8s aH = *(const v8s*)&wiH2[ai]; v8s aL = *(const v8s*)&wiL2[ai];
        di = __builtin_amdgcn_mfma_f32_16x16x32_bf16(aH, xbH[kc], di, 0,0,0);
        di = __builtin_amdgcn_mfma_f32_16x16x32_bf16(aH, xbL[kc], di, 0,0,0);
        di = __builtin_amdgcn_mfma_f32_16x16x32_bf16(aL, xbH[kc], di, 0,0,0);
        aH = *(const v8s*)&whH2[ai]; aL = *(const v8s*)&whL2[ai];
        dh = __builtin_amdgcn_mfma_f32_16x16x32_bf16(aH, h0H[kc], dh, 0,0,0);
        dh = __builtin_amdgcn_mfma_f32_16x16x32_bf16(aH, h0L[kc], dh, 0,0,0);
        dh = __builtin_amdgcn_mfma_f32_16x16x32_bf16(aL, h0H[kc], dh, 0,0,0);
      }
      gi[g] = di; gh[g] = dh;
    }
    int l0 = 16*hi2 + 4*q4;
    float4 h04 = *(const float4*)&hid[(base+node)*64 + l0];
    float hh4[4] = {h04.x, h04.y, h04.z, h04.w};
    float ho[4];
    #pragma unroll
    for (int r = 0; r < 4; r++){
      float rg = sigf(gi[0][r] + gh[0][r]);
      float zg = sigf(gi[1][r] + gh[1][r]);
      float ng = tanhfast(gi[2][r] + rg*gh[2][r]);
      ho[r] = (1.0f - zg)*ng + zg*hh4[r];
    }
    *(float4*)&out[(base+node)*64 + l0] = make_float4(ho[0], ho[1], ho[2], ho[3]);
  }
}

extern "C" void kernel_launch(void* const* d_in, const int* in_sizes, int n_in,
                              void* d_out, int out_size, void* d_ws, size_t ws_size,
                              hipStream_t stream){
  if (ws_size < (size_t)WS_FLOATS * sizeof(float)) return;
  float* ws = (float*)d_ws;
  // f32 copies still needed; MFMA weights go through the bf16-split branch
  static const int offs[20] = {OFF_WENC, OFF_BENC, 0, 0, OFF_BIHF, OFF_BHHF,
      0, 0, OFF_BIHB, OFF_BHHB, OFF_WHARD, OFF_BHARD, 0, 0, 0,
      OFF_BV, 0, 0, OFF_BIHC, OFF_BHHC};
  Prep p;
  for (int i = 0; i < 20; i++){
    p.s[i] = (const float*)d_in[3 + i];
    p.n[i] = in_sizes[3 + i];
    p.o[i] = offs[i];
  }
  // zero out f32 copies replaced by bf16 splits:
  p.n[2] = 0; p.n[3] = 0; p.n[6] = 0; p.n[7] = 0;      // Wih_f/Whh_f/Wih_b/Whh_b
  p.n[12] = 0; p.n[13] = 0; p.n[14] = 0;               // Wq/Wk/Wv
  p.n[16] = 0; p.n[17] = 0;                            // Wih_c/Whh_c
  hipLaunchKernelGGL(k_prep, dim3(96, 30), dim3(256), 0, stream, p,
                     (const float*)d_in[3], (const float*)d_in[5], (const float*)d_in[9],
                     (const float*)d_in[6], (const float*)d_in[10],
                     (const float*)d_in[15], (const float*)d_in[16], (const float*)d_in[17],
                     (const float*)d_in[19], (const float*)d_in[20], ws);
  hipLaunchKernelGGL(k_main, dim3(1024), dim3(256), 0, stream,
                     (const float*)d_in[0], (const float*)d_in[1],
                     (const float*)d_in[2], ws, (float*)d_out);
}